// Round 10
// baseline (4156.157 us; speedup 1.0000x reference)
//
#include <hip/hip_runtime.h>
#include <stdint.h>

// ---------------------------------------------------------------------------
// ConditionalDecoder: emb-gather -> LSTM x2 -> FiLM -> vocab GEMM
// B=16, T=256, V=32000, E=H=Z=256, 4H=1024
// Round 10: BATCHED per-step MFMA -- one block (1 CU) holds the whole batch;
//   A-rows = 16 samples' h (no replication; r5/r9 wasted 15/16 of MFMA and
//   idled 48/64 lanes in nonlin). 8 waves x 2/SIMD; wave owns 32 hcols x 4
//   gates. W register-resident exactly as r9 (g bf16 64 regs + i,f,o fp8 96
//   regs, same pack buffers). h in LDS, chunk-XOR swizzled (chunk ^= sp&7)
//   for conflict-free A-frag reads. Branchless e4m3. Grid=1 per layer.
// ---------------------------------------------------------------------------

#define B_  16
#define T_  256
#define H_  256
#define V_  32000
#define G4  1024

#define LTPB 512   // 8 waves

typedef unsigned short u16;
typedef unsigned long long u64;
typedef __attribute__((ext_vector_type(8))) short  short8;
typedef __attribute__((ext_vector_type(4))) short  short4v;
typedef __attribute__((ext_vector_type(4))) float  f32x4;

static __device__ __forceinline__ float bf2f(u16 u) {
  uint32_t i = ((uint32_t)u) << 16;
  return __builtin_bit_cast(float, i);
}
static __device__ __forceinline__ u16 f2bf(float f) {
  uint32_t i = __builtin_bit_cast(uint32_t, f);
  uint32_t lsb = (i >> 16) & 1u;
  i += 0x7fffu + lsb;
  return (u16)(i >> 16);
}
static __device__ __forceinline__ float sigf(float x) {
  return 1.0f / (1.0f + __expf(-x));
}
static __device__ __forceinline__ float tanhfast(float x) {
  return 1.0f - 2.0f / (1.0f + __expf(2.0f * x));
}

// OCP e4m3fn encode, branchless (RNE normals; rint subnormals; 448 clamp).
// Used for BOTH W-pack and per-step h -> A/B formats match by construction.
static __device__ __forceinline__ uint32_t f32_to_e4m3(float f) {
  float af = __builtin_fabsf(f);
  af = fminf(af, 448.0f);
  uint32_t s = (__builtin_bit_cast(uint32_t, f) >> 24) & 0x80u;
  uint32_t m = __builtin_bit_cast(uint32_t, af);
  uint32_t lsb = (m >> 20) & 1u;
  m += 0x7ffffu + lsb;
  int e = (int)(m >> 23) - 120;
  uint32_t enc = ((uint32_t)(e > 0 ? e : 0) << 3) | ((m >> 20) & 7u);
  uint32_t encs = (uint32_t)rintf(af * 512.0f);   // subnormal: q*2^-9; q==8 -> 0x08 ok
  enc = (e <= 0) ? encs : enc;
  return s | enc;
}

// ------------------------------ prep kernels -------------------------------

__global__ void k_convert(const float* __restrict__ src, u16* __restrict__ dst, int n) {
  int i = blockIdx.x * blockDim.x + threadIdx.x;
  int stride = gridDim.x * blockDim.x;
  for (; i < n; i += stride) dst[i] = f2bf(src[i]);
}

__global__ void k_addbias(const float* __restrict__ a, const float* __restrict__ b,
                          float* __restrict__ dst, int n) {
  int i = blockIdx.x * blockDim.x + threadIdx.x;
  if (i < n) dst[i] = a[i] + b[i];
}

// Pack bf16 W frags for the g (candidate) gate: 16 frags/wave (8 waves).
// idx = ((w*16 + cb*8 + ks)*64 + lane); row = 512 + w*32 + cb*16 + (lane&15);
// k = ks*32 + (lane>>4)*8 + j
__global__ void k_packWg(const float* __restrict__ Whh, u16* __restrict__ pk) {
  int i = blockIdx.x * blockDim.x + threadIdx.x;   // 8192
  int lane = i & 63;
  int fb = (i >> 6) & 15;
  int w  = i >> 10;
  int cb = fb >> 3, ks = fb & 7;
  int row = 512 + w * 32 + cb * 16 + (lane & 15);
  int kb  = ks * 32 + (lane >> 4) * 8;
  const float* src = Whh + (size_t)row * 256 + kb;
  short8 v;
  #pragma unroll
  for (int j = 0; j < 8; j++) v[j] = (short)f2bf(src[j]);
  *(short8*)(pk + (size_t)i * 8) = v;
}

// Pack fp8 W frags for gates i,f,o: 48 frags/wave (8 waves).
// idx = ((w*48 + g8*16 + cb*8 + ks)*64 + lane); gate row base {0,256,768};
// row = base + w*32 + cb*16 + (lane&15); k = ks*32 + (lane>>4)*8 + j
__global__ void k_packW8(const float* __restrict__ Whh, u64* __restrict__ pk) {
  int i = blockIdx.x * blockDim.x + threadIdx.x;   // 24576
  int lane = i & 63;
  int fo = (i >> 6) % 48;
  int w  = (i >> 6) / 48;
  int g8 = fo >> 4, cb = (fo >> 3) & 1, ks = fo & 7;
  int base = (g8 == 0) ? 0 : (g8 == 1 ? 256 : 768);
  int row = base + w * 32 + cb * 16 + (lane & 15);
  int kb  = ks * 32 + (lane >> 4) * 8;
  const float* src = Whh + (size_t)row * 256 + kb;
  u64 p = 0;
  #pragma unroll
  for (int j = 0; j < 8; j++)
    p |= ((u64)f32_to_e4m3(src[j])) << (8 * j);
  pk[i] = p;
}

// gamma = z@Wg.T + bg ; beta = z@Wb.T + bb   (each (16,256))
__global__ void k_film(const float* __restrict__ z,
                       const float* __restrict__ Wg, const float* __restrict__ bg,
                       const float* __restrict__ Wb, const float* __restrict__ bb,
                       float* __restrict__ gamma, float* __restrict__ beta) {
  int tid = blockIdx.x * blockDim.x + threadIdx.x;   // 8192
  int which = tid >> 12;
  int o = tid & 4095;
  int b = o >> 8, h = o & 255;
  const float* W  = which ? Wb : Wg;
  const float* bi = which ? bb : bg;
  float acc = bi[h];
  const float* zr = z + b * 256;
  const float* wr = W + h * 256;
  #pragma unroll 8
  for (int k = 0; k < 256; k++) acc += zr[k] * wr[k];
  (which ? beta : gamma)[o] = acc;
}

// x[b][t][:] = (seq[b][t]==0 ? 0 : emb[seq[b][t]])  as bf16
__global__ void k_gather(const int* __restrict__ seq, const float* __restrict__ emb,
                         u16* __restrict__ xb) {
  int i = blockIdx.x * blockDim.x + threadIdx.x;     // B*T*(E/4) = 262144
  int n = B_ * T_ * (H_ / 4);
  if (i >= n) return;
  int e4 = i & 63;
  int bt = i >> 6;
  int t = bt & 255, b = bt >> 8;
  int row = seq[b * 257 + t];
  short4v p;
  if (row == 0) {
    p[0] = 0; p[1] = 0; p[2] = 0; p[3] = 0;
  } else {
    const f32x4 v = *(const f32x4*)(emb + (size_t)row * 256 + e4 * 4);
    p[0] = (short)f2bf(v[0]); p[1] = (short)f2bf(v[1]);
    p[2] = (short)f2bf(v[2]); p[3] = (short)f2bf(v[3]);
  }
  *(short4v*)(xb + (size_t)bt * 256 + e4 * 4) = p;
}

// ------------------------------ bf16 GEMM ----------------------------------
// C(M,N) fp32 = A(M,K)bf16 @ B(N,K)bf16^T + bias(N). M,N mult of 128, K mult of 32.
// permX (N must be 1024): col = g*256 + r; ocol = (r>>5)*128 + (r&15)*8
//   + g*2 + ((r>>4)&1)  -> LSTM lane (w,c15) reads 8 gate values as 2 f32x4.

__global__ __launch_bounds__(256) void k_gemm_bt(
    const u16* __restrict__ A, const u16* __restrict__ Bm,
    const float* __restrict__ bias, float* __restrict__ C,
    int M, int N, int K, int permX) {
  __shared__ u16 sA[128 * 40];
  __shared__ u16 sB[128 * 40];
  const int tid  = threadIdx.x;
  const int lane = tid & 63;
  const int wv   = tid >> 6;
  const int wr   = wv >> 1, wc = wv & 1;
  const int m0 = blockIdx.y * 128, n0 = blockIdx.x * 128;
  const int rr = tid >> 2;
  const int cc = (tid & 3) * 8;

  f32x4 acc[4][4];
  #pragma unroll
  for (int m = 0; m < 4; m++)
    #pragma unroll
    for (int n = 0; n < 4; n++) acc[m][n] = (f32x4){0.f, 0.f, 0.f, 0.f};

  for (int ks = 0; ks < K; ks += 32) {
    short8 va0 = *(const short8*)(A  + (size_t)(m0 + rr)      * K + ks + cc);
    short8 va1 = *(const short8*)(A  + (size_t)(m0 + rr + 64) * K + ks + cc);
    short8 vb0 = *(const short8*)(Bm + (size_t)(n0 + rr)      * K + ks + cc);
    short8 vb1 = *(const short8*)(Bm + (size_t)(n0 + rr + 64) * K + ks + cc);
    __syncthreads();
    *(short8*)&sA[(rr)      * 40 + cc] = va0;
    *(short8*)&sA[(rr + 64) * 40 + cc] = va1;
    *(short8*)&sB[(rr)      * 40 + cc] = vb0;
    *(short8*)&sB[(rr + 64) * 40 + cc] = vb1;
    __syncthreads();
    const int kc = (lane >> 4) * 8;
    short8 af[4], bfr[4];
    #pragma unroll
    for (int m = 0; m < 4; m++)
      af[m] = *(const short8*)&sA[(wr * 64 + m * 16 + (lane & 15)) * 40 + kc];
    #pragma unroll
    for (int n = 0; n < 4; n++)
      bfr[n] = *(const short8*)&sB[(wc * 64 + n * 16 + (lane & 15)) * 40 + kc];
    #pragma unroll
    for (int m = 0; m < 4; m++)
      #pragma unroll
      for (int n = 0; n < 4; n++)
        acc[m][n] = __builtin_amdgcn_mfma_f32_16x16x32_bf16(af[m], bfr[n], acc[m][n], 0, 0, 0);
  }

  #pragma unroll
  for (int m = 0; m < 4; m++) {
    int row = m0 + wr * 64 + m * 16 + ((lane >> 4) << 2);
    #pragma unroll
    for (int n = 0; n < 4; n++) {
      int col = n0 + wc * 64 + n * 16 + (lane & 15);
      float bv = bias[col];
      int ocol = col;
      if (permX) {
        int g = col >> 8, r = col & 255;
        ocol = (r >> 5) * 128 + (r & 15) * 8 + g * 2 + ((r >> 4) & 1);
      }
      #pragma unroll
      for (int i = 0; i < 4; i++)
        C[(size_t)(row + i) * N + ocol] = acc[m][n][i] + bv;
    }
  }
}

// ------------------------- batched LSTM (1 block) --------------------------
// Grid=1, 512 thr (8 waves, 2/SIMD). A-rows = 16 samples. Wave w owns hcols
// [w*32, w*32+32) x 4 gates = 8 N-tiles; W frags as r9 (g bf16, i/f/o fp8).
// A-frag: lane reads h[sample = lane&15][k = ks*32 + (lane>>4)*8 ..+8].
// C-frag: lane holds (sample = (lane>>4)*4+i, hcol = w*32+cb*16+(lane&15)).
// h LDS swizzle: elem k lives at [sp*256 + ((k>>3)^(sp&7))*8 + (k&7)].

__global__ __launch_bounds__(LTPB, 2) void k_lstm_batch(
    const float* __restrict__ Xpre,    // (B*T, 1024) fp32, permuted
    const u16* __restrict__ WpkG,      // packed bf16 g-gate frags
    const u64* __restrict__ Wpk8,      // packed fp8 i,f,o frags
    u16* __restrict__ outb,            // (B,T,H) bf16
    const float* __restrict__ gamma, const float* __restrict__ beta,
    int mode) {
  __shared__ u16     hbuf[2][16 * 256];
  __shared__ uint8_t h8buf[2][16 * 256];

  const int tid  = threadIdx.x;
  const int lane = tid & 63;
  const int w    = tid >> 6;
  const int c15  = lane & 15;
  const int lhi  = lane >> 4;

  // ---- W frags -> registers (same pack layout as r9) ----
  short8 wgm[16];
  {
    const u16* bp = WpkG + ((size_t)(w * 16) * 64 + lane) * 8;
    #pragma unroll
    for (int f = 0; f < 16; ++f)
      wgm[f] = *(const short8*)(bp + (size_t)f * 512);
  }
  u64 w8r[48];
  {
    const u64* p8 = Wpk8 + (size_t)(w * 48) * 64 + lane;
    #pragma unroll
    for (int f = 0; f < 48; ++f)
      w8r[f] = p8[(size_t)f * 64];
  }

  // FiLM params for this lane's 8 outputs
  float gm[2][4], bt[2][4];
  #pragma unroll
  for (int cb = 0; cb < 2; ++cb)
    #pragma unroll
    for (int i = 0; i < 4; ++i) {
      int sp = lhi * 4 + i, hc = w * 32 + cb * 16 + c15;
      gm[cb][i] = mode ? gamma[sp * 256 + hc] : 1.f;
      bt[cb][i] = mode ? beta[sp * 256 + hc] : 0.f;
    }

  float cs[2][4];
  #pragma unroll
  for (int cb = 0; cb < 2; ++cb)
    #pragma unroll
    for (int i = 0; i < 4; ++i) cs[cb][i] = 0.f;

  // per-sample X row base (lane's 8 gate values per sample = 2 f32x4)
  const float* xr0 = Xpre + ((size_t)(lhi * 4 + 0) * T_) * 1024 + w * 128 + c15 * 8;
  const float* xr1 = Xpre + ((size_t)(lhi * 4 + 1) * T_) * 1024 + w * 128 + c15 * 8;
  const float* xr2 = Xpre + ((size_t)(lhi * 4 + 2) * T_) * 1024 + w * 128 + c15 * 8;
  const float* xr3 = Xpre + ((size_t)(lhi * 4 + 3) * T_) * 1024 + w * 128 + c15 * 8;

  f32x4 xa[4], xg[4];
  xa[0] = *(const f32x4*)(xr0);     xg[0] = *(const f32x4*)(xr0 + 4);
  xa[1] = *(const f32x4*)(xr1);     xg[1] = *(const f32x4*)(xr1 + 4);
  xa[2] = *(const f32x4*)(xr2);     xg[2] = *(const f32x4*)(xr2 + 4);
  xa[3] = *(const f32x4*)(xr3);     xg[3] = *(const f32x4*)(xr3 + 4);

  // ---- t = 0 (no recurrent term) ----
  #pragma unroll
  for (int cb = 0; cb < 2; ++cb)
    #pragma unroll
    for (int i = 0; i < 4; ++i) {
      int sp = lhi * 4 + i, hc = w * 32 + cb * 16 + c15;
      float cn = sigf(xa[i][cb]) * tanhfast(xg[i][cb]);
      float hn = sigf(xg[i][2 + cb]) * tanhfast(cn);
      cs[cb][i] = cn;
      u16 hv = f2bf(hn);
      int sw = ((hc >> 3) ^ (sp & 7)) * 8 + (hc & 7);
      hbuf[0][sp * 256 + sw] = hv;
      h8buf[0][sp * 256 + sw] = (uint8_t)f32_to_e4m3(hn);
      outb[((size_t)(sp * T_)) * 256 + hc] = mode ? f2bf(gm[cb][i] * hn + bt[cb][i]) : hv;
    }
  asm volatile("s_waitcnt lgkmcnt(0)" ::: "memory");
  __builtin_amdgcn_sched_barrier(0);
  __builtin_amdgcn_s_barrier();
  __builtin_amdgcn_sched_barrier(0);

  // preload X for t=1
  xa[0] = *(const f32x4*)(xr0 + 1024);  xg[0] = *(const f32x4*)(xr0 + 1028);
  xa[1] = *(const f32x4*)(xr1 + 1024);  xg[1] = *(const f32x4*)(xr1 + 1028);
  xa[2] = *(const f32x4*)(xr2 + 1024);  xg[2] = *(const f32x4*)(xr2 + 1028);
  xa[3] = *(const f32x4*)(xr3 + 1024);  xg[3] = *(const f32x4*)(xr3 + 1028);

  for (int t = 1; t < T_; ++t) {
    // prefetch X for t+1 (clamped), consumed next iteration
    const size_t xoff = (size_t)((t + 1 < T_) ? t + 1 : t) * 1024;
    f32x4 na0 = *(const f32x4*)(xr0 + xoff), ng0 = *(const f32x4*)(xr0 + xoff + 4);
    f32x4 na1 = *(const f32x4*)(xr1 + xoff), ng1 = *(const f32x4*)(xr1 + xoff + 4);
    f32x4 na2 = *(const f32x4*)(xr2 + xoff), ng2 = *(const f32x4*)(xr2 + xoff + 4);
    f32x4 na3 = *(const f32x4*)(xr3 + xoff), ng3 = *(const f32x4*)(xr3 + xoff + 4);

    const int rb = (t + 1) & 1;
    const u16*     hrd  = hbuf[rb];
    const uint8_t* h8rd = h8buf[rb];

    // ---- MFMA: gates = h(t-1) @ Whh^T  (A rows = 16 samples) ----
    f32x4 aI[2], aF[2], aG[2], aO[2];
    #pragma unroll
    for (int i = 0; i < 2; ++i) {
      aI[i] = (f32x4){0.f, 0.f, 0.f, 0.f};
      aF[i] = (f32x4){0.f, 0.f, 0.f, 0.f};
      aG[i] = (f32x4){0.f, 0.f, 0.f, 0.f};
      aO[i] = (f32x4){0.f, 0.f, 0.f, 0.f};
    }
    #pragma unroll
    for (int ks = 0; ks < 8; ++ks) {
      const int aofs = c15 * 256 + (((ks * 4 + lhi) ^ (c15 & 7)) * 8);
      short8 a  = *(const short8*)&hrd[aofs];
      u64    a8 = *(const u64*)&h8rd[aofs];
      aG[0] = __builtin_amdgcn_mfma_f32_16x16x32_bf16(a, wgm[ks],     aG[0], 0, 0, 0);
      aG[1] = __builtin_amdgcn_mfma_f32_16x16x32_bf16(a, wgm[8 + ks], aG[1], 0, 0, 0);
      aI[0] = __builtin_amdgcn_mfma_f32_16x16x32_fp8_fp8((long)a8, (long)w8r[ks],      aI[0], 0, 0, 0);
      aI[1] = __builtin_amdgcn_mfma_f32_16x16x32_fp8_fp8((long)a8, (long)w8r[8 + ks],  aI[1], 0, 0, 0);
      aF[0] = __builtin_amdgcn_mfma_f32_16x16x32_fp8_fp8((long)a8, (long)w8r[16 + ks], aF[0], 0, 0, 0);
      aF[1] = __builtin_amdgcn_mfma_f32_16x16x32_fp8_fp8((long)a8, (long)w8r[24 + ks], aF[1], 0, 0, 0);
      aO[0] = __builtin_amdgcn_mfma_f32_16x16x32_fp8_fp8((long)a8, (long)w8r[32 + ks], aO[0], 0, 0, 0);
      aO[1] = __builtin_amdgcn_mfma_f32_16x16x32_fp8_fp8((long)a8, (long)w8r[40 + ks], aO[1], 0, 0, 0);
    }

    // ---- nonlinearity: 8 (sample,hcol) outputs per lane ----
    const int wb = t & 1;
    #pragma unroll
    for (int cb = 0; cb < 2; ++cb)
      #pragma unroll
      for (int i = 0; i < 4; ++i) {
        int sp = lhi * 4 + i, hc = w * 32 + cb * 16 + c15;
        float iv = aI[cb][i] + xa[i][cb];
        float fv = aF[cb][i] + xa[i][2 + cb];
        float gv = aG[cb][i] + xg[i][cb];
        float ov = aO[cb][i] + xg[i][2 + cb];
        float cn = sigf(fv) * cs[cb][i] + sigf(iv) * tanhfast(gv);
        float hn = sigf(ov) * tanhfast(cn);
        cs[cb][i] = cn;
        u16 hv = f2bf(hn);
        int sw = ((hc >> 3) ^ (sp & 7)) * 8 + (hc & 7);
        hbuf[wb][sp * 256 + sw] = hv;
        h8buf[wb][sp * 256 + sw] = (uint8_t)f32_to_e4m3(hn);
        outb[((size_t)(sp * T_ + t)) * 256 + hc] =
            mode ? f2bf(gm[cb][i] * hn + bt[cb][i]) : hv;
      }

    // ---- raw barrier: LDS drained, VMEM left in flight ----
    asm volatile("s_waitcnt lgkmcnt(0)" ::: "memory");
    __builtin_amdgcn_sched_barrier(0);
    __builtin_amdgcn_s_barrier();
    __builtin_amdgcn_sched_barrier(0);

    xa[0] = na0; xg[0] = ng0;
    xa[1] = na1; xg[1] = ng1;
    xa[2] = na2; xg[2] = ng2;
    xa[3] = na3; xg[3] = ng3;
  }
}

// ------------------------------ launcher -----------------------------------

extern "C" void kernel_launch(void* const* d_in, const int* in_sizes, int n_in,
                              void* d_out, int out_size, void* d_ws, size_t ws_size,
                              hipStream_t stream) {
  const float* z    = (const float*)d_in[0];
  const int*   seq  = (const int*)  d_in[1];
  const float* emb  = (const float*)d_in[2];
  const float* Wg   = (const float*)d_in[3];
  const float* bg   = (const float*)d_in[4];
  const float* Wb   = (const float*)d_in[5];
  const float* bb   = (const float*)d_in[6];
  const float* Wih0 = (const float*)d_in[7];
  const float* Whh0 = (const float*)d_in[8];
  const float* bih0 = (const float*)d_in[9];
  const float* bhh0 = (const float*)d_in[10];
  const float* Wih1 = (const float*)d_in[11];
  const float* Whh1 = (const float*)d_in[12];
  const float* bih1 = (const float*)d_in[13];
  const float* bhh1 = (const float*)d_in[14];
  const float* Wout = (const float*)d_in[15];
  const float* bout = (const float*)d_in[16];

  char* ws = (char*)d_ws;
  size_t off = 0;
  auto take = [&](size_t bytes) -> char* {
    char* p = ws + off;
    off = (off + bytes + 255) & ~(size_t)255;
    return p;
  };
  float* gamma  = (float*)take(B_ * H_ * 4);
  float* beta   = (float*)take(B_ * H_ * 4);
  float* b01    = (float*)take(G4 * 4);
  float* b11    = (float*)take(G4 * 4);
  u16*   Wih0b  = (u16*)  take((size_t)G4 * H_ * 2);
  u16*   Wih1b  = (u16*)  take((size_t)G4 * H_ * 2);
  u16*   WpG0   = (u16*)  take((size_t)8 * 16 * 64 * 8 * 2);   // 128 KB
  u64*   Wp80   = (u64*)  take((size_t)8 * 48 * 64 * 8);       // 192 KB
  u16*   WpG1   = (u16*)  take((size_t)8 * 16 * 64 * 8 * 2);
  u64*   Wp81   = (u64*)  take((size_t)8 * 48 * 64 * 8);
  u16*   Woutb  = (u16*)  take((size_t)V_ * H_ * 2);
  u16*   xb     = (u16*)  take((size_t)B_ * T_ * H_ * 2);
  float* X      = (float*)take((size_t)B_ * T_ * G4 * 4);
  u16*   h1b    = (u16*)  take((size_t)B_ * T_ * H_ * 2);
  u16*   filmb  = (u16*)  take((size_t)B_ * T_ * H_ * 2);
  (void)ws_size; (void)in_sizes; (void)n_in; (void)out_size;

  // prep
  k_convert<<<256, 256, 0, stream>>>(Wih0, Wih0b, G4 * H_);
  k_convert<<<256, 256, 0, stream>>>(Wih1, Wih1b, G4 * H_);
  k_convert<<<1024, 256, 0, stream>>>(Wout, Woutb, V_ * H_);
  k_packWg<<<32, 256, 0, stream>>>(Whh0, WpG0);
  k_packW8<<<96, 256, 0, stream>>>(Whh0, Wp80);
  k_packWg<<<32, 256, 0, stream>>>(Whh1, WpG1);
  k_packW8<<<96, 256, 0, stream>>>(Whh1, Wp81);
  k_addbias<<<4, 256, 0, stream>>>(bih0, bhh0, b01, G4);
  k_addbias<<<4, 256, 0, stream>>>(bih1, bhh1, b11, G4);
  k_film<<<32, 256, 0, stream>>>(z, Wg, bg, Wb, bb, gamma, beta);
  k_gather<<<1024, 256, 0, stream>>>(seq, emb, xb);

  // layer 0 input projection (permuted X layout)
  k_gemm_bt<<<dim3(G4 / 128, (B_ * T_) / 128), 256, 0, stream>>>(
      xb, Wih0b, b01, X, B_ * T_, G4, H_, 1);

  // layer 0 recurrence: single block, whole batch in MFMA rows
  k_lstm_batch<<<1, LTPB, 0, stream>>>(X, WpG0, Wp80, h1b, gamma, beta, 0);

  // layer 1 input projection (permuted X layout)
  k_gemm_bt<<<dim3(G4 / 128, (B_ * T_) / 128), 256, 0, stream>>>(
      h1b, Wih1b, b11, X, B_ * T_, G4, H_, 1);

  // layer 1 recurrence (FiLM fused into output)
  k_lstm_batch<<<1, LTPB, 0, stream>>>(X, WpG1, Wp81, filmb, gamma, beta, 1);

  // logits = filmed @ Wout^T + b_out
  k_gemm_bt<<<dim3(V_ / 128, (B_ * T_) / 128), 256, 0, stream>>>(
      filmb, Woutb, bout, (float*)d_out, B_ * T_, V_, H_, 0);
}

// Round 11
// 746.629 us; speedup vs baseline: 5.5666x; 5.5666x over previous
//
#include <hip/hip_runtime.h>
#include <stdint.h>

// ---------------------------------------------------------------------------
// ConditionalDecoder: emb-gather -> LSTM x2 -> FiLM -> vocab GEMM
// B=16, T=256, V=32000, E=H=Z=256, 4H=1024
// Round 11: fused dataflow pipeline for the two LSTM layers.
//   One launch, grid 48: blocks 0-15 L0 recurrence (r9 code, 452us proven),
//   16-31 X1-projection workers (chunk of 16 t at a time), 32-47 L1
//   recurrence. Producer->consumer via agent-scope release/acquire flags at
//   16-step granularity (fence pattern proven in r2). L1 trails L0 by ~35us
//   instead of running after it; the separate X1 GEMM dispatch disappears.
//   LSTM per-step math unchanged from r9 (g bf16 + i,f,o fp8, W in regs).
// ---------------------------------------------------------------------------

#define B_  16
#define T_  256
#define H_  256
#define V_  32000
#define G4  1024

#define LTPB 512   // 8 waves
#define FSTR 32    // flag stride in ints (one 128B line per flag)

typedef unsigned short u16;
typedef unsigned long long u64;
typedef __attribute__((ext_vector_type(8))) short  short8;
typedef __attribute__((ext_vector_type(4))) short  short4v;
typedef __attribute__((ext_vector_type(4))) float  f32x4;

static __device__ __forceinline__ float bf2f(u16 u) {
  uint32_t i = ((uint32_t)u) << 16;
  return __builtin_bit_cast(float, i);
}
static __device__ __forceinline__ u16 f2bf(float f) {
  uint32_t i = __builtin_bit_cast(uint32_t, f);
  uint32_t lsb = (i >> 16) & 1u;
  i += 0x7fffu + lsb;
  return (u16)(i >> 16);
}
static __device__ __forceinline__ float sigf(float x) {
  return 1.0f / (1.0f + __expf(-x));
}
static __device__ __forceinline__ float tanhfast(float x) {
  return 1.0f - 2.0f / (1.0f + __expf(2.0f * x));
}

// OCP e4m3fn encode (bias 7, max 448, RNE). Same encoder for W-pack and h.
static __device__ __forceinline__ uint32_t f32_to_e4m3(float f) {
  uint32_t u = __builtin_bit_cast(uint32_t, f);
  uint32_t s = (u >> 24) & 0x80u;
  uint32_t mag = u & 0x7fffffffu;
  if (mag >= 0x43E00000u) return s | 0x7Eu;
  if (mag < 0x3C800000u) {
    float af = __builtin_bit_cast(float, mag);
    int q = (int)rintf(af * 512.0f);
    if (q >= 8) return s | 0x08u;
    return s | (uint32_t)q;
  }
  uint32_t lsb = (mag >> 20) & 1u;
  mag += 0x7ffffu + lsb;
  int e = (int)(mag >> 23) - 120;
  uint32_t m3 = (mag >> 20) & 7u;
  if (e >= 16) return s | 0x7Eu;
  return s | ((uint32_t)e << 3) | m3;
}

// ------------------------------ prep kernels -------------------------------

__global__ void k_convert(const float* __restrict__ src, u16* __restrict__ dst, int n) {
  int i = blockIdx.x * blockDim.x + threadIdx.x;
  int stride = gridDim.x * blockDim.x;
  for (; i < n; i += stride) dst[i] = f2bf(src[i]);
}

__global__ void k_addbias(const float* __restrict__ a, const float* __restrict__ b,
                          float* __restrict__ dst, int n) {
  int i = blockIdx.x * blockDim.x + threadIdx.x;
  if (i < n) dst[i] = a[i] + b[i];
}

__global__ void k_zeroi(int* __restrict__ p, int n) {
  int i = blockIdx.x * blockDim.x + threadIdx.x;
  if (i < n) p[i] = 0;
}

// Pack bf16 W frags for g gate: 16 frags/wave (8 waves).
__global__ void k_packWg(const float* __restrict__ Whh, u16* __restrict__ pk) {
  int i = blockIdx.x * blockDim.x + threadIdx.x;   // 8192
  int lane = i & 63;
  int fb = (i >> 6) & 15;
  int w  = i >> 10;
  int cb = fb >> 3, ks = fb & 7;
  int row = 512 + w * 32 + cb * 16 + (lane & 15);
  int kb  = ks * 32 + (lane >> 4) * 8;
  const float* src = Whh + (size_t)row * 256 + kb;
  short8 v;
  #pragma unroll
  for (int j = 0; j < 8; j++) v[j] = (short)f2bf(src[j]);
  *(short8*)(pk + (size_t)i * 8) = v;
}

// Pack fp8 W frags for i,f,o gates: 48 frags/wave (8 waves).
__global__ void k_packW8(const float* __restrict__ Whh, u64* __restrict__ pk) {
  int i = blockIdx.x * blockDim.x + threadIdx.x;   // 24576
  int lane = i & 63;
  int fo = (i >> 6) % 48;
  int w  = (i >> 6) / 48;
  int g8 = fo >> 4, cb = (fo >> 3) & 1, ks = fo & 7;
  int base = (g8 == 0) ? 0 : (g8 == 1 ? 256 : 768);
  int row = base + w * 32 + cb * 16 + (lane & 15);
  int kb  = ks * 32 + (lane >> 4) * 8;
  const float* src = Whh + (size_t)row * 256 + kb;
  u64 p = 0;
  #pragma unroll
  for (int j = 0; j < 8; j++)
    p |= ((u64)f32_to_e4m3(src[j])) << (8 * j);
  pk[i] = p;
}

// gamma = z@Wg.T + bg ; beta = z@Wb.T + bb
__global__ void k_film(const float* __restrict__ z,
                       const float* __restrict__ Wg, const float* __restrict__ bg,
                       const float* __restrict__ Wb, const float* __restrict__ bb,
                       float* __restrict__ gamma, float* __restrict__ beta) {
  int tid = blockIdx.x * blockDim.x + threadIdx.x;   // 8192
  int which = tid >> 12;
  int o = tid & 4095;
  int b = o >> 8, h = o & 255;
  const float* W  = which ? Wb : Wg;
  const float* bi = which ? bb : bg;
  float acc = bi[h];
  const float* zr = z + b * 256;
  const float* wr = W + h * 256;
  #pragma unroll 8
  for (int k = 0; k < 256; k++) acc += zr[k] * wr[k];
  (which ? beta : gamma)[o] = acc;
}

// x[b][t][:] = (seq[b][t]==0 ? 0 : emb[seq[b][t]])  as bf16
__global__ void k_gather(const int* __restrict__ seq, const float* __restrict__ emb,
                         u16* __restrict__ xb) {
  int i = blockIdx.x * blockDim.x + threadIdx.x;
  int n = B_ * T_ * (H_ / 4);
  if (i >= n) return;
  int e4 = i & 63;
  int bt = i >> 6;
  int t = bt & 255, b = bt >> 8;
  int row = seq[b * 257 + t];
  short4v p;
  if (row == 0) {
    p[0] = 0; p[1] = 0; p[2] = 0; p[3] = 0;
  } else {
    const f32x4 v = *(const f32x4*)(emb + (size_t)row * 256 + e4 * 4);
    p[0] = (short)f2bf(v[0]); p[1] = (short)f2bf(v[1]);
    p[2] = (short)f2bf(v[2]); p[3] = (short)f2bf(v[3]);
  }
  *(short4v*)(xb + (size_t)bt * 256 + e4 * 4) = p;
}

// ------------------------------ bf16 GEMM ----------------------------------
// permX (N=1024): col = g*256 + r; ocol = (r>>5)*128 + (r&15)*8 + g*2 + ((r>>4)&1)

__global__ __launch_bounds__(256) void k_gemm_bt(
    const u16* __restrict__ A, const u16* __restrict__ Bm,
    const float* __restrict__ bias, float* __restrict__ C,
    int M, int N, int K, int permX) {
  __shared__ u16 sA[128 * 40];
  __shared__ u16 sB[128 * 40];
  const int tid  = threadIdx.x;
  const int lane = tid & 63;
  const int wv   = tid >> 6;
  const int wr   = wv >> 1, wc = wv & 1;
  const int m0 = blockIdx.y * 128, n0 = blockIdx.x * 128;
  const int rr = tid >> 2;
  const int cc = (tid & 3) * 8;

  f32x4 acc[4][4];
  #pragma unroll
  for (int m = 0; m < 4; m++)
    #pragma unroll
    for (int n = 0; n < 4; n++) acc[m][n] = (f32x4){0.f, 0.f, 0.f, 0.f};

  for (int ks = 0; ks < K; ks += 32) {
    short8 va0 = *(const short8*)(A  + (size_t)(m0 + rr)      * K + ks + cc);
    short8 va1 = *(const short8*)(A  + (size_t)(m0 + rr + 64) * K + ks + cc);
    short8 vb0 = *(const short8*)(Bm + (size_t)(n0 + rr)      * K + ks + cc);
    short8 vb1 = *(const short8*)(Bm + (size_t)(n0 + rr + 64) * K + ks + cc);
    __syncthreads();
    *(short8*)&sA[(rr)      * 40 + cc] = va0;
    *(short8*)&sA[(rr + 64) * 40 + cc] = va1;
    *(short8*)&sB[(rr)      * 40 + cc] = vb0;
    *(short8*)&sB[(rr + 64) * 40 + cc] = vb1;
    __syncthreads();
    const int kc = (lane >> 4) * 8;
    short8 af[4], bfr[4];
    #pragma unroll
    for (int m = 0; m < 4; m++)
      af[m] = *(const short8*)&sA[(wr * 64 + m * 16 + (lane & 15)) * 40 + kc];
    #pragma unroll
    for (int n = 0; n < 4; n++)
      bfr[n] = *(const short8*)&sB[(wc * 64 + n * 16 + (lane & 15)) * 40 + kc];
    #pragma unroll
    for (int m = 0; m < 4; m++)
      #pragma unroll
      for (int n = 0; n < 4; n++)
        acc[m][n] = __builtin_amdgcn_mfma_f32_16x16x32_bf16(af[m], bfr[n], acc[m][n], 0, 0, 0);
  }

  #pragma unroll
  for (int m = 0; m < 4; m++) {
    int row = m0 + wr * 64 + m * 16 + ((lane >> 4) << 2);
    #pragma unroll
    for (int n = 0; n < 4; n++) {
      int col = n0 + wc * 64 + n * 16 + (lane & 15);
      float bv = bias[col];
      int ocol = col;
      if (permX) {
        int g = col >> 8, r = col & 255;
        ocol = (r >> 5) * 128 + (r & 15) * 8 + g * 2 + ((r >> 4) & 1);
      }
      #pragma unroll
      for (int i = 0; i < 4; i++)
        C[(size_t)(row + i) * N + ocol] = acc[m][n][i] + bv;
    }
  }
}

// --------------------- fused two-layer pipeline kernel ---------------------
// Grid 48 x 512. Blocks 0-15: L0 recurrence (producer of h1b, flagA).
// Blocks 16-31: X1 projection (consume flagA, produce X1 + flagB).
// Blocks 32-47: L1 recurrence (consume flagB, produce filmb).

static __device__ __forceinline__ void lstm_role(
    const float* __restrict__ Xpre, const u16* __restrict__ WpkG,
    const u64* __restrict__ Wpk8, u16* __restrict__ outb,
    const float* __restrict__ gamma, const float* __restrict__ beta,
    int mode, int s, int* flagOut, const int* flagIn,
    u16 (*hbuf)[256], u64 (*h8buf)[32]) {
  const int tid  = threadIdx.x;
  const int lane = tid & 63;
  const int w    = tid >> 6;
  const int l15  = lane & 15;
  const int lhi  = lane >> 4;

  // ---- W frags -> registers (r9 layout) ----
  short8 wgm[16];
  {
    const u16* bp = WpkG + ((size_t)(w * 16) * 64 + lane) * 8;
    #pragma unroll
    for (int f = 0; f < 16; ++f)
      wgm[f] = *(const short8*)(bp + (size_t)f * 512);
  }
  u64 w8r[48];
  {
    const u64* p8 = Wpk8 + (size_t)(w * 48) * 64 + lane;
    #pragma unroll
    for (int f = 0; f < 48; ++f)
      w8r[f] = p8[(size_t)f * 64];
  }

  const int col0 = w * 32 + l15;
  const int col1 = col0 + 16;
  float cs0 = 0.f, cs1 = 0.f;
  float gm0 = 1.f, gm1 = 1.f, bt0 = 0.f, bt1 = 0.f;
  if (mode) {
    gm0 = gamma[s * 256 + col0]; bt0 = beta[s * 256 + col0];
    gm1 = gamma[s * 256 + col1]; bt1 = beta[s * 256 + col1];
  }

  // consumer: wait for first X chunk before any X load
  if (flagIn) {
    if (tid == 0) {
      while (__hip_atomic_load(flagIn, __ATOMIC_RELAXED,
                               __HIP_MEMORY_SCOPE_AGENT) < 1) { }
    }
    __syncthreads();
    __builtin_amdgcn_fence(__ATOMIC_ACQUIRE, "agent");
  }

  const float* xptr = Xpre + (size_t)s * T_ * 1024 + (size_t)(w * 16 + l15) * 8;

  // ---- t = 0 ----
  f32x4 xa = *(const f32x4*)(xptr);
  f32x4 xg = *(const f32x4*)(xptr + 4);
  {
    float cn0 = sigf(xa[2]) * cs0 + sigf(xa[0]) * tanhfast(xg[0]);
    float hn0 = sigf(xg[2]) * tanhfast(cn0);
    cs0 = cn0;
    float cn1 = sigf(xa[3]) * cs1 + sigf(xa[1]) * tanhfast(xg[1]);
    float hn1 = sigf(xg[3]) * tanhfast(cn1);
    cs1 = cn1;
    u16 h0 = f2bf(hn0), h1 = f2bf(hn1);
    if (lhi == 0) {
      hbuf[0][col0] = h0;
      hbuf[0][col1] = h1;
      ((uint8_t*)h8buf[0])[col0] = (uint8_t)f32_to_e4m3(hn0);
      ((uint8_t*)h8buf[0])[col1] = (uint8_t)f32_to_e4m3(hn1);
      outb[(size_t)(s * T_) * 256 + col0] = mode ? f2bf(gm0 * hn0 + bt0) : h0;
      outb[(size_t)(s * T_) * 256 + col1] = mode ? f2bf(gm1 * hn1 + bt1) : h1;
    }
  }
  asm volatile("s_waitcnt lgkmcnt(0)" ::: "memory");
  __builtin_amdgcn_sched_barrier(0);
  __builtin_amdgcn_s_barrier();
  __builtin_amdgcn_sched_barrier(0);

  xa = *(const f32x4*)(xptr + 1024);
  xg = *(const f32x4*)(xptr + 1024 + 4);

  for (int t = 1; t < T_; ++t) {
    // consumer gate before prefetching into a new 16-step chunk
    if (flagIn && (t & 15) == 15 && (t + 1) < T_) {
      const int need = ((t + 1) >> 4) + 1;
      if (tid == 0) {
        while (__hip_atomic_load(flagIn, __ATOMIC_RELAXED,
                                 __HIP_MEMORY_SCOPE_AGENT) < need) { }
      }
      __syncthreads();
      __builtin_amdgcn_fence(__ATOMIC_ACQUIRE, "agent");
    }

    const float* xn = xptr + (size_t)((t + 1 < T_) ? t + 1 : t) * 1024;
    f32x4 na = *(const f32x4*)(xn);
    f32x4 ng = *(const f32x4*)(xn + 4);

    const u16* hrd  = hbuf[(t + 1) & 1];
    const u64* h8rd = h8buf[(t + 1) & 1];

    f32x4 aI[2], aF[2], aG[2], aO[2];
    #pragma unroll
    for (int i = 0; i < 2; ++i) {
      aI[i] = (f32x4){0.f, 0.f, 0.f, 0.f};
      aF[i] = (f32x4){0.f, 0.f, 0.f, 0.f};
      aG[i] = (f32x4){0.f, 0.f, 0.f, 0.f};
      aO[i] = (f32x4){0.f, 0.f, 0.f, 0.f};
    }
    #pragma unroll
    for (int ks = 0; ks < 8; ++ks) {
      short8 a  = *(const short8*)&hrd[ks * 32 + lhi * 8];
      u64    a8 = h8rd[ks * 4 + lhi];
      aG[0] = __builtin_amdgcn_mfma_f32_16x16x32_bf16(a, wgm[ks],     aG[0], 0, 0, 0);
      aG[1] = __builtin_amdgcn_mfma_f32_16x16x32_bf16(a, wgm[8 + ks], aG[1], 0, 0, 0);
      aI[0] = __builtin_amdgcn_mfma_f32_16x16x32_fp8_fp8((long)a8, (long)w8r[ks],      aI[0], 0, 0, 0);
      aI[1] = __builtin_amdgcn_mfma_f32_16x16x32_fp8_fp8((long)a8, (long)w8r[8 + ks],  aI[1], 0, 0, 0);
      aF[0] = __builtin_amdgcn_mfma_f32_16x16x32_fp8_fp8((long)a8, (long)w8r[16 + ks], aF[0], 0, 0, 0);
      aF[1] = __builtin_amdgcn_mfma_f32_16x16x32_fp8_fp8((long)a8, (long)w8r[24 + ks], aF[1], 0, 0, 0);
      aO[0] = __builtin_amdgcn_mfma_f32_16x16x32_fp8_fp8((long)a8, (long)w8r[32 + ks], aO[0], 0, 0, 0);
      aO[1] = __builtin_amdgcn_mfma_f32_16x16x32_fp8_fp8((long)a8, (long)w8r[40 + ks], aO[1], 0, 0, 0);
    }

    float iv0 = aI[0][0] + xa[0], iv1 = aI[1][0] + xa[1];
    float fv0 = aF[0][0] + xa[2], fv1 = aF[1][0] + xa[3];
    float gv0 = aG[0][0] + xg[0], gv1 = aG[1][0] + xg[1];
    float ov0 = aO[0][0] + xg[2], ov1 = aO[1][0] + xg[3];

    float cn0 = sigf(fv0) * cs0 + sigf(iv0) * tanhfast(gv0);
    float hn0 = sigf(ov0) * tanhfast(cn0);
    cs0 = cn0;
    float cn1 = sigf(fv1) * cs1 + sigf(iv1) * tanhfast(gv1);
    float hn1 = sigf(ov1) * tanhfast(cn1);
    cs1 = cn1;

    u16 h0 = f2bf(hn0), h1 = f2bf(hn1);
    if (lhi == 0) {
      hbuf[t & 1][col0] = h0;
      hbuf[t & 1][col1] = h1;
      ((uint8_t*)h8buf[t & 1])[col0] = (uint8_t)f32_to_e4m3(hn0);
      ((uint8_t*)h8buf[t & 1])[col1] = (uint8_t)f32_to_e4m3(hn1);
      outb[((size_t)(s * T_ + t)) * 256 + col0] = mode ? f2bf(gm0 * hn0 + bt0) : h0;
      outb[((size_t)(s * T_ + t)) * 256 + col1] = mode ? f2bf(gm1 * hn1 + bt1) : h1;
    }

    // end-of-step: signal (with full drain) every 16 steps, else raw barrier
    if (flagOut && (t & 15) == 15) {
      __syncthreads();
      if (tid == 0) {
        __builtin_amdgcn_fence(__ATOMIC_RELEASE, "agent");
        __hip_atomic_store(flagOut, t + 1, __ATOMIC_RELAXED,
                           __HIP_MEMORY_SCOPE_AGENT);
      }
    } else {
      asm volatile("s_waitcnt lgkmcnt(0)" ::: "memory");
      __builtin_amdgcn_sched_barrier(0);
      __builtin_amdgcn_s_barrier();
      __builtin_amdgcn_sched_barrier(0);
    }

    xa = na;
    xg = ng;
  }
}

static __device__ __forceinline__ void xg_role(
    const u16* __restrict__ h1b, const u16* __restrict__ Wih1b,
    const float* __restrict__ b11, float* __restrict__ X1,
    int s, const int* flagA, int* flagB) {
  const int tid  = threadIdx.x;
  const int lane = tid & 63;
  const int w    = tid >> 6;
  const int l15  = lane & 15;
  const int lhi  = lane >> 4;

  for (int tc = 0; tc < 16; ++tc) {
    const int need = (tc + 1) * 16;
    if (tid == 0) {
      while (__hip_atomic_load(flagA, __ATOMIC_RELAXED,
                               __HIP_MEMORY_SCOPE_AGENT) < need) { }
    }
    __syncthreads();
    __builtin_amdgcn_fence(__ATOMIC_ACQUIRE, "agent");

    const int t0 = tc * 16;
    // A-frags: h1 rows t0..t0+15, K=256
    short8 afr[8];
    #pragma unroll
    for (int ks = 0; ks < 8; ++ks)
      afr[ks] = *(const short8*)(h1b + ((size_t)(s * T_ + t0 + l15)) * 256 + ks * 32 + lhi * 8);

    // wave w covers gate cols [w*128, w*128+128) = 8 N-tiles
    #pragma unroll
    for (int nt = 0; nt < 8; ++nt) {
      const int colb = w * 128 + nt * 16 + l15;
      f32x4 acc = (f32x4){0.f, 0.f, 0.f, 0.f};
      const u16* bp = Wih1b + (size_t)colb * 256 + lhi * 8;
      #pragma unroll
      for (int ks = 0; ks < 8; ++ks) {
        short8 bf = *(const short8*)(bp + ks * 32);
        acc = __builtin_amdgcn_mfma_f32_16x16x32_bf16(afr[ks], bf, acc, 0, 0, 0);
      }
      const int g = colb >> 8, r = colb & 255;
      const int ocol = (r >> 5) * 128 + (r & 15) * 8 + g * 2 + ((r >> 4) & 1);
      const float bv = b11[colb];
      #pragma unroll
      for (int i = 0; i < 4; ++i) {
        int trow = t0 + lhi * 4 + i;
        X1[((size_t)(s * T_ + trow)) * 1024 + ocol] = acc[i] + bv;
      }
    }

    __syncthreads();   // drains vmcnt for all waves before signaling
    if (tid == 0) {
      __builtin_amdgcn_fence(__ATOMIC_RELEASE, "agent");
      __hip_atomic_store(flagB, tc + 1, __ATOMIC_RELAXED,
                         __HIP_MEMORY_SCOPE_AGENT);
    }
  }
}

__global__ __launch_bounds__(LTPB, 2) void k_fused(
    const float* __restrict__ X0, float* __restrict__ X1,
    const u16* __restrict__ WpG0, const u64* __restrict__ Wp80,
    const u16* __restrict__ WpG1, const u64* __restrict__ Wp81,
    const u16* __restrict__ Wih1b, const float* __restrict__ b11,
    u16* __restrict__ h1b, u16* __restrict__ filmb,
    const float* __restrict__ gamma, const float* __restrict__ beta,
    int* __restrict__ flagA, int* __restrict__ flagB) {
  __shared__ u16 hbuf[2][256];
  __shared__ u64 h8buf[2][32];
  const int role = blockIdx.x >> 4;
  const int s    = blockIdx.x & 15;
  if (role == 0) {
    lstm_role(X0, WpG0, Wp80, h1b, gamma, beta, 0, s,
              &flagA[s * FSTR], nullptr, hbuf, h8buf);
  } else if (role == 1) {
    xg_role(h1b, Wih1b, b11, X1, s, &flagA[s * FSTR], &flagB[s * FSTR]);
  } else {
    lstm_role(X1, WpG1, Wp81, filmb, gamma, beta, 1, s,
              nullptr, &flagB[s * FSTR], hbuf, h8buf);
  }
}

// ------------------------------ launcher -----------------------------------

extern "C" void kernel_launch(void* const* d_in, const int* in_sizes, int n_in,
                              void* d_out, int out_size, void* d_ws, size_t ws_size,
                              hipStream_t stream) {
  const float* z    = (const float*)d_in[0];
  const int*   seq  = (const int*)  d_in[1];
  const float* emb  = (const float*)d_in[2];
  const float* Wg   = (const float*)d_in[3];
  const float* bg   = (const float*)d_in[4];
  const float* Wb   = (const float*)d_in[5];
  const float* bb   = (const float*)d_in[6];
  const float* Wih0 = (const float*)d_in[7];
  const float* Whh0 = (const float*)d_in[8];
  const float* bih0 = (const float*)d_in[9];
  const float* bhh0 = (const float*)d_in[10];
  const float* Wih1 = (const float*)d_in[11];
  const float* Whh1 = (const float*)d_in[12];
  const float* bih1 = (const float*)d_in[13];
  const float* bhh1 = (const float*)d_in[14];
  const float* Wout = (const float*)d_in[15];
  const float* bout = (const float*)d_in[16];

  char* ws = (char*)d_ws;
  size_t off = 0;
  auto take = [&](size_t bytes) -> char* {
    char* p = ws + off;
    off = (off + bytes + 255) & ~(size_t)255;
    return p;
  };
  float* gamma  = (float*)take(B_ * H_ * 4);
  float* beta   = (float*)take(B_ * H_ * 4);
  float* b01    = (float*)take(G4 * 4);
  float* b11    = (float*)take(G4 * 4);
  u16*   Wih0b  = (u16*)  take((size_t)G4 * H_ * 2);
  u16*   Wih1b  = (u16*)  take((size_t)G4 * H_ * 2);
  u16*   WpG0   = (u16*)  take((size_t)8 * 16 * 64 * 8 * 2);
  u64*   Wp80   = (u64*)  take((size_t)8 * 48 * 64 * 8);
  u16*   WpG1   = (u16*)  take((size_t)8 * 16 * 64 * 8 * 2);
  u64*   Wp81   = (u64*)  take((size_t)8 * 48 * 64 * 8);
  u16*   Woutb  = (u16*)  take((size_t)V_ * H_ * 2);
  u16*   xb     = (u16*)  take((size_t)B_ * T_ * H_ * 2);
  float* X0     = (float*)take((size_t)B_ * T_ * G4 * 4);
  float* X1     = (float*)take((size_t)B_ * T_ * G4 * 4);
  u16*   h1b    = (u16*)  take((size_t)B_ * T_ * H_ * 2);
  u16*   filmb  = (u16*)  take((size_t)B_ * T_ * H_ * 2);
  int*   flagA  = (int*)  take(B_ * FSTR * 4);
  int*   flagB  = (int*)  take(B_ * FSTR * 4);
  (void)ws_size; (void)in_sizes; (void)n_in; (void)out_size;

  // prep
  k_convert<<<256, 256, 0, stream>>>(Wih0, Wih0b, G4 * H_);
  k_convert<<<256, 256, 0, stream>>>(Wih1, Wih1b, G4 * H_);
  k_convert<<<1024, 256, 0, stream>>>(Wout, Woutb, V_ * H_);
  k_packWg<<<32, 256, 0, stream>>>(Whh0, WpG0);
  k_packW8<<<96, 256, 0, stream>>>(Whh0, Wp80);
  k_packWg<<<32, 256, 0, stream>>>(Whh1, WpG1);
  k_packW8<<<96, 256, 0, stream>>>(Whh1, Wp81);
  k_addbias<<<4, 256, 0, stream>>>(bih0, bhh0, b01, G4);
  k_addbias<<<4, 256, 0, stream>>>(bih1, bhh1, b11, G4);
  k_zeroi<<<4, 256, 0, stream>>>(flagA, 2 * B_ * FSTR);   // flagA + flagB
  k_film<<<32, 256, 0, stream>>>(z, Wg, bg, Wb, bb, gamma, beta);
  k_gather<<<1024, 256, 0, stream>>>(seq, emb, xb);

  // layer 0 input projection (permuted X layout)
  k_gemm_bt<<<dim3(G4 / 128, (B_ * T_) / 128), 256, 0, stream>>>(
      xb, Wih0b, b01, X0, B_ * T_, G4, H_, 1);

  // fused pipeline: L0 recurrence || X1 projection || L1 recurrence
  k_fused<<<48, LTPB, 0, stream>>>(X0, X1, WpG0, Wp80, WpG1, Wp81,
                                   Wih1b, b11, h1b, filmb, gamma, beta,
                                   flagA, flagB);

  // logits = filmed @ Wout^T + b_out
  k_gemm_bt<<<dim3(V_ / 128, (B_ * T_) / 128), 256, 0, stream>>>(
      filmb, Woutb, bout, (float*)d_out, B_ * T_, V_, H_, 0);
}